// Round 4
// baseline (319.439 us; speedup 1.0000x reference)
//
#include <hip/hip_runtime.h>
#include <math.h>

#define TT 1024
#define DD 512
#define KK 64
#define OO 1024
#define EPSF 1e-12f

typedef __attribute__((ext_vector_type(8))) short bf16x8;
typedef __attribute__((ext_vector_type(4))) float f32x4;

__device__ __forceinline__ ushort f2bf(float f) {
  unsigned u = __float_as_uint(f);
  u = (u + 0x7FFFu + ((u >> 16) & 1u)) >> 16;
  return (ushort)u;
}
__device__ __forceinline__ float bf2f(ushort h) {
  return __uint_as_float(((unsigned)h) << 16);
}

// ws layout (float units, 512 MiB available):
//  aT     bf16[32][64][1024]   @ [0, 1M)
//  xbfT   bf16[32][512][1024]  @ [1M, 9M)
//  xaggP  f32 [4][32][64][512] @ [9M, 13M)
//  full   f32 [32*64*512]      @ [13M, 14M)
//  fullbf bf16[32][32768]      @ [14M, 14.5M)
//  outP   f32 [64][32][1024]   @ [15M, 17M)
//  whT    bf16[64][512]        @ [17M) ; sum_w/s1/scale after

// ---------------- K0: whT[k][d] <- weight[d][k]; zero sum_w ----------------
__global__ __launch_bounds__(256) void nv_k0(const float* __restrict__ w,
                                             ushort* __restrict__ whT,
                                             float* __restrict__ sum_w) {
  int idx = blockIdx.x * 256 + threadIdx.x;
  if (idx < 32768) {
    int d = idx >> 6, k = idx & 63;
    whT[(size_t)k * DD + d] = f2bf(w[idx]);
  } else if (idx < 32768 + 2048) {
    sum_w[idx - 32768] = 0.f;
  }
}

// ---------------- K1: softmax(x@W+b) -> aT bf16; also emits xbfT bf16, sum_w ----------------
__global__ __launch_bounds__(256) void nv_k1(
    const float* __restrict__ x, const ushort* __restrict__ whT,
    const float* __restrict__ bias, ushort* __restrict__ aT,
    ushort* __restrict__ xbfT, float* __restrict__ sum_w) {
  const int b = blockIdx.y, t0 = blockIdx.x * 64;
  const int tid = threadIdx.x;
  const int wave = tid >> 6, lane = tid & 63, l15 = lane & 15, q = lane >> 4;

  __shared__ ushort xs[64 * 64];   // [t][d-granule], slot g^(t&7)
  __shared__ ushort xsT[64 * 64];  // [d][t-granule], slot tg^((d>>3)&7)
  __shared__ ushort wsm[64 * 64];  // [k][d-granule], slot g^(k&7)

  f32x4 acc[4];
#pragma unroll
  for (int nt = 0; nt < 4; ++nt)
#pragma unroll
    for (int r = 0; r < 4; ++r) acc[nt][r] = 0.f;

  for (int dc = 0; dc < DD; dc += 64) {
    __syncthreads();
#pragma unroll
    for (int it = 0; it < 2; ++it) {
      int gi = it * 256 + tid;
      int t = gi >> 3, gd = gi & 7;
      const float* px = x + (size_t)(b * TT + t0 + t) * DD + dc + gd * 8;
      float4 v0 = *(const float4*)px;
      float4 v1 = *(const float4*)(px + 4);
      ushort u[8];
      u[0] = f2bf(v0.x); u[1] = f2bf(v0.y); u[2] = f2bf(v0.z); u[3] = f2bf(v0.w);
      u[4] = f2bf(v1.x); u[5] = f2bf(v1.y); u[6] = f2bf(v1.z); u[7] = f2bf(v1.w);
      bf16x8 pk;
#pragma unroll
      for (int i = 0; i < 8; ++i) pk[i] = (short)u[i];
      *(bf16x8*)(xs + t * 64 + ((gd ^ (t & 7)) << 3)) = pk;
      int tg = t >> 3;
#pragma unroll
      for (int i = 0; i < 8; ++i) {
        int d = gd * 8 + i;
        xsT[d * 64 + ((tg ^ ((d >> 3) & 7)) << 3) + (t & 7)] = u[i];
      }
    }
#pragma unroll
    for (int it = 0; it < 2; ++it) {
      int gi = it * 256 + tid;
      int k = gi >> 3, gd = gi & 7;
      bf16x8 v = *(const bf16x8*)(whT + (size_t)k * DD + dc + gd * 8);
      *(bf16x8*)(wsm + k * 64 + ((gd ^ (k & 7)) << 3)) = v;
    }
    __syncthreads();
    // MFMA
#pragma unroll
    for (int kc = 0; kc < 2; ++kc) {
      int gq = kc * 4 + q;
      int t = wave * 16 + l15;
      bf16x8 af = *(const bf16x8*)(xs + t * 64 + ((gq ^ (t & 7)) << 3));
#pragma unroll
      for (int nt = 0; nt < 4; ++nt) {
        int k = nt * 16 + l15;
        bf16x8 bfv = *(const bf16x8*)(wsm + k * 64 + ((gq ^ (k & 7)) << 3));
        acc[nt] = __builtin_amdgcn_mfma_f32_16x16x32_bf16(af, bfv, acc[nt], 0, 0, 0);
      }
    }
    // xbfT write-out from xsT
#pragma unroll
    for (int it = 0; it < 2; ++it) {
      int gi = it * 256 + tid;
      int d = gi >> 3, g = gi & 7;
      bf16x8 v = *(const bf16x8*)(xsT + d * 64 + (g << 3));
      int tg = g ^ ((d >> 3) & 7);
      *(bf16x8*)(xbfT + (size_t)(b * DD + dc + d) * TT + t0 + tg * 8) = v;
    }
  }

  // softmax epilogue (rows t = wave*16 + q*4 + r; cols k = nt*16 + l15)
  float bia[4];
#pragma unroll
  for (int nt = 0; nt < 4; ++nt) bia[nt] = bias[nt * 16 + l15];

  ushort au[4][4];
  float sw[4] = {0.f, 0.f, 0.f, 0.f};
#pragma unroll
  for (int r = 0; r < 4; ++r) {
    float l[4];
#pragma unroll
    for (int nt = 0; nt < 4; ++nt) l[nt] = acc[nt][r] + bia[nt];
    float m = fmaxf(fmaxf(l[0], l[1]), fmaxf(l[2], l[3]));
#pragma unroll
    for (int s = 1; s <= 8; s <<= 1) m = fmaxf(m, __shfl_xor(m, s));
    float e[4];
#pragma unroll
    for (int nt = 0; nt < 4; ++nt) e[nt] = __expf(l[nt] - m);
    float ssum = e[0] + e[1] + e[2] + e[3];
#pragma unroll
    for (int s = 1; s <= 8; s <<= 1) ssum += __shfl_xor(ssum, s);
    float inv = 1.f / ssum;
#pragma unroll
    for (int nt = 0; nt < 4; ++nt) {
      ushort u = f2bf(e[nt] * inv);
      au[nt][r] = u;
      sw[nt] += bf2f(u);
    }
  }
#pragma unroll
  for (int nt = 0; nt < 4; ++nt) {
    float s = sw[nt];
    s += __shfl_xor(s, 16);
    s += __shfl_xor(s, 32);
    if (q == 0) atomicAdd(sum_w + b * KK + nt * 16 + l15, s);
  }
  // transpose a-tile -> aT[b][k][t] via xs
  __syncthreads();
#pragma unroll
  for (int nt = 0; nt < 4; ++nt)
#pragma unroll
    for (int r = 0; r < 4; ++r) {
      int k = nt * 16 + l15;
      int t = wave * 16 + q * 4 + r;
      xs[k * 64 + (((t >> 3) ^ (k & 7)) << 3) + (t & 7)] = au[nt][r];
    }
  __syncthreads();
#pragma unroll
  for (int it = 0; it < 2; ++it) {
    int gi = it * 256 + tid;
    int k = gi >> 3, g = gi & 7;
    bf16x8 v = *(const bf16x8*)(xs + k * 64 + (g << 3));
    int tg = g ^ (k & 7);
    *(bf16x8*)(aT + (size_t)(b * KK + k) * TT + t0 + tg * 8) = v;
  }
}

// ---------------- K2: xaggP[tsp][b][k][d] via MFMA, pure b128 staging ----------------
__global__ __launch_bounds__(256) void nv_k2(
    const ushort* __restrict__ aT, const ushort* __restrict__ xbfT,
    float* __restrict__ xaggP) {
  const int d0 = blockIdx.x * 64;
  const int b = blockIdx.y;
  const int tsp = blockIdx.z;
  const int tid = threadIdx.x;
  const int wave = tid >> 6, lane = tid & 63, l15 = lane & 15, q = lane >> 4;

  __shared__ ushort asx[64 * 64];  // [k][t-granule], slot g^(k&7)
  __shared__ ushort xsb[64 * 64];  // [d][t-granule], slot g^(d&7)

  f32x4 acc[4];
#pragma unroll
  for (int nt = 0; nt < 4; ++nt)
#pragma unroll
    for (int r = 0; r < 4; ++r) acc[nt][r] = 0.f;

  for (int tc = 0; tc < 4; ++tc) {
    const int t0 = tsp * 256 + tc * 64;
    __syncthreads();
#pragma unroll
    for (int it = 0; it < 2; ++it) {
      int gi = it * 256 + tid;
      int k = gi >> 3, g = gi & 7;
      bf16x8 v = *(const bf16x8*)(aT + (size_t)(b * KK + k) * TT + t0 + g * 8);
      *(bf16x8*)(asx + k * 64 + ((g ^ (k & 7)) << 3)) = v;
    }
#pragma unroll
    for (int it = 0; it < 2; ++it) {
      int gi = it * 256 + tid;
      int d = gi >> 3, g = gi & 7;
      bf16x8 v = *(const bf16x8*)(xbfT + (size_t)(b * DD + d0 + d) * TT + t0 + g * 8);
      *(bf16x8*)(xsb + d * 64 + ((g ^ (d & 7)) << 3)) = v;
    }
    __syncthreads();
#pragma unroll
    for (int kc = 0; kc < 2; ++kc) {
      int gq = kc * 4 + q;
      int k = wave * 16 + l15;
      bf16x8 af = *(const bf16x8*)(asx + k * 64 + ((gq ^ (k & 7)) << 3));
#pragma unroll
      for (int nt = 0; nt < 4; ++nt) {
        int d = nt * 16 + l15;
        bf16x8 bfv = *(const bf16x8*)(xsb + d * 64 + ((gq ^ (d & 7)) << 3));
        acc[nt] = __builtin_amdgcn_mfma_f32_16x16x32_bf16(af, bfv, acc[nt], 0, 0, 0);
      }
    }
  }
#pragma unroll
  for (int nt = 0; nt < 4; ++nt)
#pragma unroll
    for (int r = 0; r < 4; ++r) {
      int k = wave * 16 + q * 4 + r;
      xaggP[(size_t)((tsp * 32 + b) * KK + k) * DD + d0 + nt * 16 + l15] = acc[nt][r];
    }
}

// ---------------- K3a: sum 4 partials, residual, per-(b,k) sumsq ----------------
__global__ __launch_bounds__(128) void nv_k3a(
    const float* __restrict__ xaggP, float* __restrict__ full,
    const float* __restrict__ centers, const float* __restrict__ sum_w,
    float* __restrict__ s1) {
  const int k = blockIdx.x, b = blockIdx.y;
  const int tid = threadIdx.x;
  const float sw = sum_w[b * KK + k];
  float4 v = make_float4(0.f, 0.f, 0.f, 0.f);
#pragma unroll
  for (int sp = 0; sp < 4; ++sp) {
    float4 p = *((const float4*)(xaggP + (size_t)((sp * 32 + b) * KK + k) * DD) + tid);
    v.x += p.x; v.y += p.y; v.z += p.z; v.w += p.w;
  }
  float4 c = *((const float4*)(centers + (size_t)k * DD) + tid);
  v.x = fmaf(-sw, c.x, v.x);
  v.y = fmaf(-sw, c.y, v.y);
  v.z = fmaf(-sw, c.z, v.z);
  v.w = fmaf(-sw, c.w, v.w);
  *((float4*)(full + (size_t)(b * KK + k) * DD) + tid) = v;
  float ss = v.x * v.x + v.y * v.y + v.z * v.z + v.w * v.w;
#pragma unroll
  for (int s = 1; s <= 32; s <<= 1) ss += __shfl_xor(ss, s);
  __shared__ float red[2];
  if ((tid & 63) == 0) red[tid >> 6] = ss;
  __syncthreads();
  if (tid == 0) s1[b * KK + k] = red[0] + red[1];
}

// ---------------- K3b: per-(b,k) combined scale ----------------
__global__ __launch_bounds__(64) void nv_k3b(const float* __restrict__ s1,
                                             float* __restrict__ scale) {
  const int b = blockIdx.x, k = threadIdx.x;
  float r = s1[b * KK + k];
  float d1 = fmaxf(r, EPSF);
  float s2 = r / d1;
#pragma unroll
  for (int s = 1; s <= 32; s <<= 1) s2 += __shfl_xor(s2, s);
  scale[b * KK + k] = rsqrtf(d1) * rsqrtf(fmaxf(s2, EPSF));
}

// ---------------- K3c: scale + convert -> fullbf bf16 ----------------
__global__ __launch_bounds__(128) void nv_k3c(const float* __restrict__ full,
                                              const float* __restrict__ scale,
                                              ushort* __restrict__ fullbf) {
  const int blk = blockIdx.x;  // b*K + k
  const float sc = scale[blk];
  float4 v = *((const float4*)(full + (size_t)blk * DD) + threadIdx.x);
  ushort4 o;
  o.x = f2bf(v.x * sc); o.y = f2bf(v.y * sc);
  o.z = f2bf(v.z * sc); o.w = f2bf(v.w * sc);
  *((ushort4*)(fullbf + (size_t)blk * DD) + threadIdx.x) = o;
}

// ---------------- K4: outP[split][32][1024], bf16-A staged->fp32, fp32 FMA ----------------
__global__ __launch_bounds__(256) void nv_k4(
    const ushort* __restrict__ fullbf, const float* __restrict__ reduc,
    float* __restrict__ outP) {
  const int c_base = blockIdx.x * 64;   // 16 col tiles
  const int r_base = blockIdx.y * 512;  // 64 row splits
  const int tid = threadIdx.x;
  const int tx = tid & 15;
  const int ty = (tid >> 4) & 3;
  const int tz = tid >> 6;
  const int c0 = c_base + tx * 4;

  __shared__ float As2[32 * 128];  // 16 KB fp32, converted from bf16

  float acc[8][4] = {};

  for (int ch = 0; ch < 4; ++ch) {
    const int rch = r_base + ch * 128;
    __syncthreads();
#pragma unroll
    for (int it = 0; it < 2; ++it) {
      int gi = it * 256 + tid;
      int bb = gi >> 4, g = gi & 15;
      bf16x8 v = *(const bf16x8*)(fullbf + (size_t)bb * 32768 + rch + g * 8);
      float4 lo, hi;
      lo.x = bf2f((ushort)v[0]); lo.y = bf2f((ushort)v[1]);
      lo.z = bf2f((ushort)v[2]); lo.w = bf2f((ushort)v[3]);
      hi.x = bf2f((ushort)v[4]); hi.y = bf2f((ushort)v[5]);
      hi.z = bf2f((ushort)v[6]); hi.w = bf2f((ushort)v[7]);
      *(float4*)(As2 + bb * 128 + g * 8) = lo;
      *(float4*)(As2 + bb * 128 + g * 8 + 4) = hi;
    }
    __syncthreads();
#pragma unroll 4
    for (int i = 0; i < 8; ++i) {
      const int rl = i * 16 + ty * 4;
      float wv[4][4];
#pragma unroll
      for (int j = 0; j < 4; ++j) {
        float4 w = *(const float4*)(reduc + (size_t)(rch + rl + j) * OO + c0);
        wv[j][0] = w.x; wv[j][1] = w.y; wv[j][2] = w.z; wv[j][3] = w.w;
      }
#pragma unroll
      for (int bb = 0; bb < 8; ++bb) {
        float4 a4 = *(const float4*)(As2 + (tz * 8 + bb) * 128 + rl);
        float a_[4] = {a4.x, a4.y, a4.z, a4.w};
#pragma unroll
        for (int j = 0; j < 4; ++j) {
          acc[bb][0] = fmaf(a_[j], wv[j][0], acc[bb][0]);
          acc[bb][1] = fmaf(a_[j], wv[j][1], acc[bb][1]);
          acc[bb][2] = fmaf(a_[j], wv[j][2], acc[bb][2]);
          acc[bb][3] = fmaf(a_[j], wv[j][3], acc[bb][3]);
        }
      }
    }
  }

#pragma unroll
  for (int bb = 0; bb < 8; ++bb) {
    float4 v = make_float4(acc[bb][0], acc[bb][1], acc[bb][2], acc[bb][3]);
    v.x += __shfl_xor(v.x, 16); v.x += __shfl_xor(v.x, 32);
    v.y += __shfl_xor(v.y, 16); v.y += __shfl_xor(v.y, 32);
    v.z += __shfl_xor(v.z, 16); v.z += __shfl_xor(v.z, 32);
    v.w += __shfl_xor(v.w, 16); v.w += __shfl_xor(v.w, 32);
    if (ty == 0) {
      *(float4*)(outP + (size_t)(blockIdx.y * 32 + tz * 8 + bb) * OO + c0) = v;
    }
  }
}

// ---------------- K5: out = sum over 64 row-splits ----------------
__global__ __launch_bounds__(256) void nv_k5(const float* __restrict__ outP,
                                             float* __restrict__ out) {
  const int idx = blockIdx.x * 256 + threadIdx.x;
  float s = 0.f;
#pragma unroll 8
  for (int sp = 0; sp < 64; ++sp) s += outP[(size_t)sp * 32768 + idx];
  out[idx] = s;
}

extern "C" void kernel_launch(void* const* d_in, const int* in_sizes, int n_in,
                              void* d_out, int out_size, void* d_ws, size_t ws_size,
                              hipStream_t stream) {
  const float* x = (const float*)d_in[0];
  const float* weight = (const float*)d_in[1];
  const float* bias = (const float*)d_in[2];
  const float* centers = (const float*)d_in[3];
  const float* reduc = (const float*)d_in[4];
  float* out = (float*)d_out;
  float* ws = (float*)d_ws;

  ushort* aT = (ushort*)ws;                       // [0, 1M)
  ushort* xbfT = (ushort*)(ws + 1048576);         // [1M, 9M)
  float* xaggP = ws + 9437184;                    // [9M, 13M)
  float* full = ws + 13631488;                    // [13M, 14M)
  ushort* fullbf = (ushort*)(ws + 14680064);      // [14M, 14.5M)
  float* outP = ws + 15728640;                    // [15M, 17M)
  ushort* whT = (ushort*)(ws + 17825792);         // [17M)
  float* sum_w = ws + 17825792 + 16384;
  float* s1 = sum_w + 2048;
  float* scale = sum_w + 4096;

  nv_k0<<<136, 256, 0, stream>>>(weight, whT, sum_w);
  nv_k1<<<dim3(16, 32), 256, 0, stream>>>(x, whT, bias, aT, xbfT, sum_w);
  nv_k2<<<dim3(8, 32, 4), 256, 0, stream>>>(aT, xbfT, xaggP);
  nv_k3a<<<dim3(64, 32), 128, 0, stream>>>(xaggP, full, centers, sum_w, s1);
  nv_k3b<<<32, 64, 0, stream>>>(s1, scale);
  nv_k3c<<<2048, 128, 0, stream>>>(full, scale, fullbf);
  nv_k4<<<dim3(16, 64), 256, 0, stream>>>(fullbf, reduc, outP);
  nv_k5<<<128, 256, 0, stream>>>(outP, out);
}

// Round 5
// 293.317 us; speedup vs baseline: 1.0891x; 1.0891x over previous
//
#include <hip/hip_runtime.h>
#include <math.h>

#define TT 1024
#define DD 512
#define KK 64
#define OO 1024
#define EPSF 1e-12f

typedef __attribute__((ext_vector_type(8))) short bf16x8;
typedef __attribute__((ext_vector_type(4))) float f32x4;

__device__ __forceinline__ ushort f2bf(float f) {
  unsigned u = __float_as_uint(f);
  u = (u + 0x7FFFu + ((u >> 16) & 1u)) >> 16;
  return (ushort)u;
}
__device__ __forceinline__ float bf2f(ushort h) {
  return __uint_as_float(((unsigned)h) << 16);
}

// ws layout (float units):
//  aT     bf16[32][64][1024]   @ [0, 1M)
//  xbfT   bf16[32][512][1024]  @ [1M, 9M)
//  xaggP  f32 [4][32][64][512] @ [9M, 13M)
//  full   f32 [32][64*512]     @ [13M, 14M)
//  fullT  f32 [32768][32]      @ [14M, 15M)
//  outP   f32 [128][32][1024]  @ [15M, 19M)
//  whT    bf16[64][512]        @ [19M) ; sum_w/s1/scale after

// ---------------- K0: whT[k][d] <- weight[d][k]; zero sum_w ----------------
__global__ __launch_bounds__(256) void nv_k0(const float* __restrict__ w,
                                             ushort* __restrict__ whT,
                                             float* __restrict__ sum_w) {
  int idx = blockIdx.x * 256 + threadIdx.x;
  if (idx < 32768) {
    int d = idx >> 6, k = idx & 63;
    whT[(size_t)k * DD + d] = f2bf(w[idx]);
  } else if (idx < 32768 + 2048) {
    sum_w[idx - 32768] = 0.f;
  }
}

// ---------------- K1: softmax(x@W+b) -> aT bf16; also emits xbfT bf16, sum_w ----------------
__global__ __launch_bounds__(256) void nv_k1(
    const float* __restrict__ x, const ushort* __restrict__ whT,
    const float* __restrict__ bias, ushort* __restrict__ aT,
    ushort* __restrict__ xbfT, float* __restrict__ sum_w) {
  const int b = blockIdx.y, t0 = blockIdx.x * 64;
  const int tid = threadIdx.x;
  const int wave = tid >> 6, lane = tid & 63, l15 = lane & 15, q = lane >> 4;

  __shared__ ushort xs[64 * 64];   // [t][d-granule], slot g^(t&7)
  __shared__ ushort xsT[64 * 64];  // [d][t-granule], slot tg^((d>>3)&7)
  __shared__ ushort wsm[64 * 64];  // [k][d-granule], slot g^(k&7)

  f32x4 acc[4];
#pragma unroll
  for (int nt = 0; nt < 4; ++nt)
#pragma unroll
    for (int r = 0; r < 4; ++r) acc[nt][r] = 0.f;

  for (int dc = 0; dc < DD; dc += 64) {
    __syncthreads();
#pragma unroll
    for (int it = 0; it < 2; ++it) {
      int gi = it * 256 + tid;
      int t = gi >> 3, gd = gi & 7;
      const float* px = x + (size_t)(b * TT + t0 + t) * DD + dc + gd * 8;
      float4 v0 = *(const float4*)px;
      float4 v1 = *(const float4*)(px + 4);
      ushort u[8];
      u[0] = f2bf(v0.x); u[1] = f2bf(v0.y); u[2] = f2bf(v0.z); u[3] = f2bf(v0.w);
      u[4] = f2bf(v1.x); u[5] = f2bf(v1.y); u[6] = f2bf(v1.z); u[7] = f2bf(v1.w);
      bf16x8 pk;
#pragma unroll
      for (int i = 0; i < 8; ++i) pk[i] = (short)u[i];
      *(bf16x8*)(xs + t * 64 + ((gd ^ (t & 7)) << 3)) = pk;
      int tg = t >> 3;
#pragma unroll
      for (int i = 0; i < 8; ++i) {
        int d = gd * 8 + i;
        xsT[d * 64 + ((tg ^ ((d >> 3) & 7)) << 3) + (t & 7)] = u[i];
      }
    }
#pragma unroll
    for (int it = 0; it < 2; ++it) {
      int gi = it * 256 + tid;
      int k = gi >> 3, gd = gi & 7;
      bf16x8 v = *(const bf16x8*)(whT + (size_t)k * DD + dc + gd * 8);
      *(bf16x8*)(wsm + k * 64 + ((gd ^ (k & 7)) << 3)) = v;
    }
    __syncthreads();
    // MFMA
#pragma unroll
    for (int kc = 0; kc < 2; ++kc) {
      int gq = kc * 4 + q;
      int t = wave * 16 + l15;
      bf16x8 af = *(const bf16x8*)(xs + t * 64 + ((gq ^ (t & 7)) << 3));
#pragma unroll
      for (int nt = 0; nt < 4; ++nt) {
        int k = nt * 16 + l15;
        bf16x8 bfv = *(const bf16x8*)(wsm + k * 64 + ((gq ^ (k & 7)) << 3));
        acc[nt] = __builtin_amdgcn_mfma_f32_16x16x32_bf16(af, bfv, acc[nt], 0, 0, 0);
      }
    }
    // xbfT write-out from xsT
#pragma unroll
    for (int it = 0; it < 2; ++it) {
      int gi = it * 256 + tid;
      int d = gi >> 3, g = gi & 7;
      bf16x8 v = *(const bf16x8*)(xsT + d * 64 + (g << 3));
      int tg = g ^ ((d >> 3) & 7);
      *(bf16x8*)(xbfT + (size_t)(b * DD + dc + d) * TT + t0 + tg * 8) = v;
    }
  }

  // softmax epilogue (rows t = wave*16 + q*4 + r; cols k = nt*16 + l15)
  float bia[4];
#pragma unroll
  for (int nt = 0; nt < 4; ++nt) bia[nt] = bias[nt * 16 + l15];

  ushort au[4][4];
  float sw[4] = {0.f, 0.f, 0.f, 0.f};
#pragma unroll
  for (int r = 0; r < 4; ++r) {
    float l[4];
#pragma unroll
    for (int nt = 0; nt < 4; ++nt) l[nt] = acc[nt][r] + bia[nt];
    float m = fmaxf(fmaxf(l[0], l[1]), fmaxf(l[2], l[3]));
#pragma unroll
    for (int s = 1; s <= 8; s <<= 1) m = fmaxf(m, __shfl_xor(m, s));
    float e[4];
#pragma unroll
    for (int nt = 0; nt < 4; ++nt) e[nt] = __expf(l[nt] - m);
    float ssum = e[0] + e[1] + e[2] + e[3];
#pragma unroll
    for (int s = 1; s <= 8; s <<= 1) ssum += __shfl_xor(ssum, s);
    float inv = 1.f / ssum;
#pragma unroll
    for (int nt = 0; nt < 4; ++nt) {
      ushort u = f2bf(e[nt] * inv);
      au[nt][r] = u;
      sw[nt] += bf2f(u);
    }
  }
#pragma unroll
  for (int nt = 0; nt < 4; ++nt) {
    float s = sw[nt];
    s += __shfl_xor(s, 16);
    s += __shfl_xor(s, 32);
    if (q == 0) atomicAdd(sum_w + b * KK + nt * 16 + l15, s);
  }
  // transpose a-tile -> aT[b][k][t] via xs
  __syncthreads();
#pragma unroll
  for (int nt = 0; nt < 4; ++nt)
#pragma unroll
    for (int r = 0; r < 4; ++r) {
      int k = nt * 16 + l15;
      int t = wave * 16 + q * 4 + r;
      xs[k * 64 + (((t >> 3) ^ (k & 7)) << 3) + (t & 7)] = au[nt][r];
    }
  __syncthreads();
#pragma unroll
  for (int it = 0; it < 2; ++it) {
    int gi = it * 256 + tid;
    int k = gi >> 3, g = gi & 7;
    bf16x8 v = *(const bf16x8*)(xs + k * 64 + (g << 3));
    int tg = g ^ (k & 7);
    *(bf16x8*)(aT + (size_t)(b * KK + k) * TT + t0 + tg * 8) = v;
  }
}

// ---------------- K2: xaggP[tsp][b][k][d] via MFMA, pure b128 staging ----------------
__global__ __launch_bounds__(256) void nv_k2(
    const ushort* __restrict__ aT, const ushort* __restrict__ xbfT,
    float* __restrict__ xaggP) {
  const int d0 = blockIdx.x * 64;
  const int b = blockIdx.y;
  const int tsp = blockIdx.z;
  const int tid = threadIdx.x;
  const int wave = tid >> 6, lane = tid & 63, l15 = lane & 15, q = lane >> 4;

  __shared__ ushort asx[64 * 64];  // [k][t-granule], slot g^(k&7)
  __shared__ ushort xsb[64 * 64];  // [d][t-granule], slot g^(d&7)

  f32x4 acc[4];
#pragma unroll
  for (int nt = 0; nt < 4; ++nt)
#pragma unroll
    for (int r = 0; r < 4; ++r) acc[nt][r] = 0.f;

  for (int tc = 0; tc < 4; ++tc) {
    const int t0 = tsp * 256 + tc * 64;
    __syncthreads();
#pragma unroll
    for (int it = 0; it < 2; ++it) {
      int gi = it * 256 + tid;
      int k = gi >> 3, g = gi & 7;
      bf16x8 v = *(const bf16x8*)(aT + (size_t)(b * KK + k) * TT + t0 + g * 8);
      *(bf16x8*)(asx + k * 64 + ((g ^ (k & 7)) << 3)) = v;
    }
#pragma unroll
    for (int it = 0; it < 2; ++it) {
      int gi = it * 256 + tid;
      int d = gi >> 3, g = gi & 7;
      bf16x8 v = *(const bf16x8*)(xbfT + (size_t)(b * DD + d0 + d) * TT + t0 + g * 8);
      *(bf16x8*)(xsb + d * 64 + ((g ^ (d & 7)) << 3)) = v;
    }
    __syncthreads();
#pragma unroll
    for (int kc = 0; kc < 2; ++kc) {
      int gq = kc * 4 + q;
      int k = wave * 16 + l15;
      bf16x8 af = *(const bf16x8*)(asx + k * 64 + ((gq ^ (k & 7)) << 3));
#pragma unroll
      for (int nt = 0; nt < 4; ++nt) {
        int d = nt * 16 + l15;
        bf16x8 bfv = *(const bf16x8*)(xsb + d * 64 + ((gq ^ (d & 7)) << 3));
        acc[nt] = __builtin_amdgcn_mfma_f32_16x16x32_bf16(af, bfv, acc[nt], 0, 0, 0);
      }
    }
  }
#pragma unroll
  for (int nt = 0; nt < 4; ++nt)
#pragma unroll
    for (int r = 0; r < 4; ++r) {
      int k = wave * 16 + q * 4 + r;
      xaggP[(size_t)((tsp * 32 + b) * KK + k) * DD + d0 + nt * 16 + l15] = acc[nt][r];
    }
}

// ---------------- K3a: sum 4 partials, residual, per-(b,k) sumsq ----------------
__global__ __launch_bounds__(128) void nv_k3a(
    const float* __restrict__ xaggP, float* __restrict__ full,
    const float* __restrict__ centers, const float* __restrict__ sum_w,
    float* __restrict__ s1) {
  const int k = blockIdx.x, b = blockIdx.y;
  const int tid = threadIdx.x;
  const float sw = sum_w[b * KK + k];
  float4 v = make_float4(0.f, 0.f, 0.f, 0.f);
#pragma unroll
  for (int sp = 0; sp < 4; ++sp) {
    float4 p = *((const float4*)(xaggP + (size_t)((sp * 32 + b) * KK + k) * DD) + tid);
    v.x += p.x; v.y += p.y; v.z += p.z; v.w += p.w;
  }
  float4 c = *((const float4*)(centers + (size_t)k * DD) + tid);
  v.x = fmaf(-sw, c.x, v.x);
  v.y = fmaf(-sw, c.y, v.y);
  v.z = fmaf(-sw, c.z, v.z);
  v.w = fmaf(-sw, c.w, v.w);
  *((float4*)(full + (size_t)(b * KK + k) * DD) + tid) = v;
  float ss = v.x * v.x + v.y * v.y + v.z * v.z + v.w * v.w;
#pragma unroll
  for (int s = 1; s <= 32; s <<= 1) ss += __shfl_xor(ss, s);
  __shared__ float red[2];
  if ((tid & 63) == 0) red[tid >> 6] = ss;
  __syncthreads();
  if (tid == 0) s1[b * KK + k] = red[0] + red[1];
}

// ---------------- K3b: per-(b,k) combined scale ----------------
__global__ __launch_bounds__(64) void nv_k3b(const float* __restrict__ s1,
                                             float* __restrict__ scale) {
  const int b = blockIdx.x, k = threadIdx.x;
  float r = s1[b * KK + k];
  float d1 = fmaxf(r, EPSF);
  float s2 = r / d1;
#pragma unroll
  for (int s = 1; s <= 32; s <<= 1) s2 += __shfl_xor(s2, s);
  scale[b * KK + k] = rsqrtf(d1) * rsqrtf(fmaxf(s2, EPSF));
}

// ---------------- K3c: scale + transpose -> fullT f32 [r=k*512+d][b] ----------------
__global__ __launch_bounds__(128) void nv_k3c(const float* __restrict__ full,
                                              const float* __restrict__ scale,
                                              float* __restrict__ fullT) {
  const int blk = blockIdx.x;  // b*K + k
  const int b = blk >> 6, k = blk & 63;
  const float sc = scale[blk];
  float4 v = *((const float4*)(full + (size_t)blk * DD) + threadIdx.x);
  int r0 = k * DD + threadIdx.x * 4;
  fullT[(size_t)(r0 + 0) * 32 + b] = v.x * sc;
  fullT[(size_t)(r0 + 1) * 32 + b] = v.y * sc;
  fullT[(size_t)(r0 + 2) * 32 + b] = v.z * sc;
  fullT[(size_t)(r0 + 3) * 32 + b] = v.w * sc;
}

// ---------------- K4: GEMV-bundle. out = full[32,32768] @ reduc[32768,1024] ----------------
// grid (4 col-strips of 256, 128 k-splits of 256). Each wave owns a 64-k subrange,
// all 32 batches, 256 cols (4/lane). fullT staged to LDS once (contiguous 32 KB).
__global__ __launch_bounds__(256, 2) void nv_k4(
    const float* __restrict__ fullT, const float* __restrict__ reduc,
    float* __restrict__ outP) {
  const int strip = blockIdx.x;   // 4
  const int ksp = blockIdx.y;     // 128
  const int tid = threadIdx.x;
  const int wave = tid >> 6, lane = tid & 63;
  const int c0 = strip * 256 + lane * 4;
  const int kblk = ksp * 256;

  __shared__ float fst[256 * 32];  // [k_local][b], 32 KB; later reused as red[32][256]

  // stage fullT rows kblk..kblk+255 (contiguous 32 KB)
#pragma unroll
  for (int it = 0; it < 8; ++it) {
    int f4 = it * 256 + tid;
    *(float4*)(fst + f4 * 4) = *(const float4*)(fullT + (size_t)kblk * 32 + f4 * 4);
  }
  __syncthreads();

  float4 acc[32];
#pragma unroll
  for (int b = 0; b < 32; ++b) acc[b] = make_float4(0.f, 0.f, 0.f, 0.f);

  const int kw = wave * 64;
#pragma unroll 2
  for (int kk = 0; kk < 64; ++kk) {
    const int kl = kw + kk;
    float4 rv = *(const float4*)(reduc + (size_t)(kblk + kl) * OO + c0);
#pragma unroll
    for (int b4 = 0; b4 < 8; ++b4) {
      float4 fv = *(const float4*)(fst + kl * 32 + b4 * 4);
      acc[b4 * 4 + 0].x = fmaf(fv.x, rv.x, acc[b4 * 4 + 0].x);
      acc[b4 * 4 + 0].y = fmaf(fv.x, rv.y, acc[b4 * 4 + 0].y);
      acc[b4 * 4 + 0].z = fmaf(fv.x, rv.z, acc[b4 * 4 + 0].z);
      acc[b4 * 4 + 0].w = fmaf(fv.x, rv.w, acc[b4 * 4 + 0].w);
      acc[b4 * 4 + 1].x = fmaf(fv.y, rv.x, acc[b4 * 4 + 1].x);
      acc[b4 * 4 + 1].y = fmaf(fv.y, rv.y, acc[b4 * 4 + 1].y);
      acc[b4 * 4 + 1].z = fmaf(fv.y, rv.z, acc[b4 * 4 + 1].z);
      acc[b4 * 4 + 1].w = fmaf(fv.y, rv.w, acc[b4 * 4 + 1].w);
      acc[b4 * 4 + 2].x = fmaf(fv.z, rv.x, acc[b4 * 4 + 2].x);
      acc[b4 * 4 + 2].y = fmaf(fv.z, rv.y, acc[b4 * 4 + 2].y);
      acc[b4 * 4 + 2].z = fmaf(fv.z, rv.z, acc[b4 * 4 + 2].z);
      acc[b4 * 4 + 2].w = fmaf(fv.z, rv.w, acc[b4 * 4 + 2].w);
      acc[b4 * 4 + 3].x = fmaf(fv.w, rv.x, acc[b4 * 4 + 3].x);
      acc[b4 * 4 + 3].y = fmaf(fv.w, rv.y, acc[b4 * 4 + 3].y);
      acc[b4 * 4 + 3].z = fmaf(fv.w, rv.z, acc[b4 * 4 + 3].z);
      acc[b4 * 4 + 3].w = fmaf(fv.w, rv.w, acc[b4 * 4 + 3].w);
    }
  }

  // cross-wave reduction in LDS (reuse fst as red[32][256])
  __syncthreads();
  for (int w = 0; w < 4; ++w) {
    if (wave == w) {
      if (w == 0) {
#pragma unroll
        for (int b = 0; b < 32; ++b)
          *(float4*)(fst + b * 256 + lane * 4) = acc[b];
      } else {
#pragma unroll
        for (int b = 0; b < 32; ++b) {
          float4 v = *(float4*)(fst + b * 256 + lane * 4);
          v.x += acc[b].x; v.y += acc[b].y; v.z += acc[b].z; v.w += acc[b].w;
          *(float4*)(fst + b * 256 + lane * 4) = v;
        }
      }
    }
    __syncthreads();
  }

  // write block partial: outP[ksp][b][strip*256 + c]
#pragma unroll
  for (int it = 0; it < 8; ++it) {
    int f4 = it * 256 + tid;      // 2048 float4s
    int b = f4 >> 6, cg = f4 & 63;
    *(float4*)(outP + ((size_t)(ksp * 32 + b) * OO) + strip * 256 + cg * 4) =
        *(const float4*)(fst + b * 256 + cg * 4);
  }
}

// ---------------- K5: out = sum over 128 k-splits ----------------
__global__ __launch_bounds__(256) void nv_k5(const float* __restrict__ outP,
                                             float* __restrict__ out) {
  const int idx = blockIdx.x * 256 + threadIdx.x;  // 0..32767 (b*1024+c)
  float s = 0.f;
#pragma unroll 8
  for (int sp = 0; sp < 128; ++sp) s += outP[(size_t)sp * 32768 + idx];
  out[idx] = s;
}

extern "C" void kernel_launch(void* const* d_in, const int* in_sizes, int n_in,
                              void* d_out, int out_size, void* d_ws, size_t ws_size,
                              hipStream_t stream) {
  const float* x = (const float*)d_in[0];
  const float* weight = (const float*)d_in[1];
  const float* bias = (const float*)d_in[2];
  const float* centers = (const float*)d_in[3];
  const float* reduc = (const float*)d_in[4];
  float* out = (float*)d_out;
  float* ws = (float*)d_ws;

  ushort* aT = (ushort*)ws;                       // [0, 1M)
  ushort* xbfT = (ushort*)(ws + 1048576);         // [1M, 9M)
  float* xaggP = ws + 9437184;                    // [9M, 13M)
  float* full = ws + 13631488;                    // [13M, 14M)
  float* fullT = ws + 14680064;                   // [14M, 15M)
  float* outP = ws + 15728640;                    // [15M, 19M)
  ushort* whT = (ushort*)(ws + 19922944);         // [19M)
  float* sum_w = ws + 19922944 + 16384;
  float* s1 = sum_w + 2048;
  float* scale = sum_w + 4096;

  nv_k0<<<136, 256, 0, stream>>>(weight, whT, sum_w);
  nv_k1<<<dim3(16, 32), 256, 0, stream>>>(x, whT, bias, aT, xbfT, sum_w);
  nv_k2<<<dim3(8, 32, 4), 256, 0, stream>>>(aT, xbfT, xaggP);
  nv_k3a<<<dim3(64, 32), 128, 0, stream>>>(xaggP, full, centers, sum_w, s1);
  nv_k3b<<<32, 64, 0, stream>>>(s1, scale);
  nv_k3c<<<2048, 128, 0, stream>>>(full, scale, fullT);
  nv_k4<<<dim3(4, 128), 256, 0, stream>>>(fullT, reduc, outP);
  nv_k5<<<128, 256, 0, stream>>>(outP, out);
}

// Round 6
// 290.275 us; speedup vs baseline: 1.1005x; 1.0105x over previous
//
#include <hip/hip_runtime.h>
#include <math.h>

#define TT 1024
#define DD 512
#define KK 64
#define OO 1024
#define EPSF 1e-12f

typedef __attribute__((ext_vector_type(8))) short bf16x8;
typedef __attribute__((ext_vector_type(4))) float f32x4;

__device__ __forceinline__ ushort f2bf(float f) {
  unsigned u = __float_as_uint(f);
  u = (u + 0x7FFFu + ((u >> 16) & 1u)) >> 16;
  return (ushort)u;
}
__device__ __forceinline__ float bf2f(ushort h) {
  return __uint_as_float(((unsigned)h) << 16);
}

// ws layout (float units):
//  xaggP  f32 [8][32][64][512] = 8388608 @ 0
//  full   f32 [32][64*512]     = 1048576 @ 8388608
//  fullT  f32 [32768][32]      = 1048576 @ 9437184
//  outP   f32 [128][32][1024]  = 4194304 @ 10485760
//  whT    bf16[64][512]        = 16384 f @ 14680064
//  sum_w  @ 14696448 ; s1 +2048 ; scale +4096

// ---------------- K0: whT[k][d] <- weight[d][k]; zero sum_w ----------------
__global__ __launch_bounds__(256) void nv_k0(const float* __restrict__ w,
                                             ushort* __restrict__ whT,
                                             float* __restrict__ sum_w) {
  int idx = blockIdx.x * 256 + threadIdx.x;
  if (idx < 32768) {
    int d = idx >> 6, k = idx & 63;
    whT[(size_t)k * DD + d] = f2bf(w[idx]);
  } else if (idx < 32768 + 2048) {
    sum_w[idx - 32768] = 0.f;
  }
}

// ---------------- K12: fused softmax-assign + aggregate ----------------
// block: (tsp, b), t-tile = 128. Phase A: a = softmax(x@W+b) (MFMA, aT kept in
// LDS only). Phase B: xaggP[tsp][b][k][d] = aT @ x (MFMA, A-frags hoisted).
__global__ __launch_bounds__(256) void nv_k12(
    const float* __restrict__ x, const ushort* __restrict__ whT,
    const float* __restrict__ bias, float* __restrict__ xaggP,
    float* __restrict__ sum_w) {
  const int tsp = blockIdx.x, b = blockIdx.y;
  const int t0 = tsp * 128;
  const int tid = threadIdx.x;
  const int wave = tid >> 6, lane = tid & 63, l15 = lane & 15, q = lane >> 4;

  __shared__ ushort xs[128 * 64];   // [t][d-granule], slot g^(t&7)      16 KB
  __shared__ ushort wsm[64 * 64];   // [k][d-granule], slot g^(k&7)       8 KB
  __shared__ ushort aTl[64 * 128];  // [k][t-granule], slot tg^(k&15)    16 KB
  __shared__ ushort xsT[64 * 128];  // [d][t-granule], slot tg^(d&15)    16 KB

  // ---------- phase A ----------
  f32x4 acc[2][4];
#pragma unroll
  for (int mt = 0; mt < 2; ++mt)
#pragma unroll
    for (int nt = 0; nt < 4; ++nt)
#pragma unroll
      for (int r = 0; r < 4; ++r) acc[mt][nt][r] = 0.f;

  for (int dc = 0; dc < DD; dc += 64) {
    __syncthreads();
#pragma unroll
    for (int it = 0; it < 4; ++it) {
      int gi = it * 256 + tid;
      int t = gi >> 3, gd = gi & 7;
      const float* px = x + (size_t)(b * TT + t0 + t) * DD + dc + gd * 8;
      float4 v0 = *(const float4*)px;
      float4 v1 = *(const float4*)(px + 4);
      bf16x8 pk;
      pk[0] = (short)f2bf(v0.x); pk[1] = (short)f2bf(v0.y);
      pk[2] = (short)f2bf(v0.z); pk[3] = (short)f2bf(v0.w);
      pk[4] = (short)f2bf(v1.x); pk[5] = (short)f2bf(v1.y);
      pk[6] = (short)f2bf(v1.z); pk[7] = (short)f2bf(v1.w);
      *(bf16x8*)(xs + t * 64 + ((gd ^ (t & 7)) << 3)) = pk;
    }
#pragma unroll
    for (int it = 0; it < 2; ++it) {
      int gi = it * 256 + tid;
      int k = gi >> 3, gd = gi & 7;
      bf16x8 v = *(const bf16x8*)(whT + (size_t)k * DD + dc + gd * 8);
      *(bf16x8*)(wsm + k * 64 + ((gd ^ (k & 7)) << 3)) = v;
    }
    __syncthreads();
#pragma unroll
    for (int kc = 0; kc < 2; ++kc) {
      int gq = kc * 4 + q;
      bf16x8 bfv[4];
#pragma unroll
      for (int nt = 0; nt < 4; ++nt) {
        int k = nt * 16 + l15;
        bfv[nt] = *(const bf16x8*)(wsm + k * 64 + ((gq ^ (k & 7)) << 3));
      }
#pragma unroll
      for (int mt = 0; mt < 2; ++mt) {
        int t = wave * 32 + mt * 16 + l15;
        bf16x8 af = *(const bf16x8*)(xs + t * 64 + ((gq ^ (t & 7)) << 3));
#pragma unroll
        for (int nt = 0; nt < 4; ++nt)
          acc[mt][nt] = __builtin_amdgcn_mfma_f32_16x16x32_bf16(af, bfv[nt], acc[mt][nt], 0, 0, 0);
      }
    }
  }

  // softmax epilogue: rows t = wave*32 + mt*16 + q*4 + r; cols k = nt*16 + l15
  float bia[4];
#pragma unroll
  for (int nt = 0; nt < 4; ++nt) bia[nt] = bias[nt * 16 + l15];

  ushort au[2][4][4];
  float sw[4] = {0.f, 0.f, 0.f, 0.f};
#pragma unroll
  for (int mt = 0; mt < 2; ++mt)
#pragma unroll
    for (int r = 0; r < 4; ++r) {
      float l[4];
#pragma unroll
      for (int nt = 0; nt < 4; ++nt) l[nt] = acc[mt][nt][r] + bia[nt];
      float m = fmaxf(fmaxf(l[0], l[1]), fmaxf(l[2], l[3]));
#pragma unroll
      for (int s = 1; s <= 8; s <<= 1) m = fmaxf(m, __shfl_xor(m, s));
      float e[4];
#pragma unroll
      for (int nt = 0; nt < 4; ++nt) e[nt] = __expf(l[nt] - m);
      float ssum = e[0] + e[1] + e[2] + e[3];
#pragma unroll
      for (int s = 1; s <= 8; s <<= 1) ssum += __shfl_xor(ssum, s);
      float inv = 1.f / ssum;
#pragma unroll
      for (int nt = 0; nt < 4; ++nt) {
        ushort u = f2bf(e[nt] * inv);
        au[mt][nt][r] = u;
        sw[nt] += bf2f(u);
      }
    }
#pragma unroll
  for (int nt = 0; nt < 4; ++nt) {
    float s = sw[nt];
    s += __shfl_xor(s, 16);
    s += __shfl_xor(s, 32);
    if (q == 0) atomicAdd(sum_w + b * KK + nt * 16 + l15, s);
  }
  // write aT into LDS: aTl[k][t], slot (t>>3)^(k&15)
#pragma unroll
  for (int mt = 0; mt < 2; ++mt)
#pragma unroll
    for (int nt = 0; nt < 4; ++nt)
#pragma unroll
      for (int r = 0; r < 4; ++r) {
        int k = nt * 16 + l15;
        int t = wave * 32 + mt * 16 + q * 4 + r;
        aTl[k * 128 + (((t >> 3) ^ (k & 15)) << 3) + (t & 7)] = au[mt][nt][r];
      }
  __syncthreads();

  // ---------- phase B ----------
  // hoist A-frags (d-invariant): afB[mk][ks], k = mk*16+l15, t-granule = ks*4+q
  bf16x8 afB[4][4];
#pragma unroll
  for (int mk = 0; mk < 4; ++mk)
#pragma unroll
    for (int ks = 0; ks < 4; ++ks) {
      int k = mk * 16 + l15;
      int g = ks * 4 + q;
      afB[mk][ks] = *(const bf16x8*)(aTl + k * 128 + ((g ^ (k & 15)) << 3));
    }

  for (int dc = 0; dc < DD; dc += 64) {
    __syncthreads();
    // transpose-stage x[t0..t0+127][dc..dc+63] -> xsT[d][t] bf16
#pragma unroll
    for (int it = 0; it < 8; ++it) {
      int fi = it * 256 + tid;
      int t = fi >> 4, dq = fi & 15;
      float4 v = *(const float4*)(x + (size_t)(b * TT + t0 + t) * DD + dc + dq * 4);
      int tg = t >> 3;
      float vv[4] = {v.x, v.y, v.z, v.w};
#pragma unroll
      for (int i = 0; i < 4; ++i) {
        int d = dq * 4 + i;
        xsT[d * 128 + ((tg ^ (d & 15)) << 3) + (t & 7)] = f2bf(vv[i]);
      }
    }
    __syncthreads();
    f32x4 accB[4];
#pragma unroll
    for (int mk = 0; mk < 4; ++mk)
#pragma unroll
      for (int r = 0; r < 4; ++r) accB[mk][r] = 0.f;
#pragma unroll
    for (int ks = 0; ks < 4; ++ks) {
      int d = wave * 16 + l15;
      int g = ks * 4 + q;
      bf16x8 bfv = *(const bf16x8*)(xsT + d * 128 + ((g ^ (d & 15)) << 3));
#pragma unroll
      for (int mk = 0; mk < 4; ++mk)
        accB[mk] = __builtin_amdgcn_mfma_f32_16x16x32_bf16(afB[mk][ks], bfv, accB[mk], 0, 0, 0);
    }
    // write: row k = mk*16 + q*4 + r, col d = dc + wave*16 + l15
#pragma unroll
    for (int mk = 0; mk < 4; ++mk)
#pragma unroll
      for (int r = 0; r < 4; ++r) {
        int k = mk * 16 + q * 4 + r;
        xaggP[(size_t)((tsp * 32 + b) * KK + k) * DD + dc + wave * 16 + l15] = accB[mk][r];
      }
  }
}

// ---------------- K3a: sum 8 partials, residual, per-(b,k) sumsq ----------------
__global__ __launch_bounds__(128) void nv_k3a(
    const float* __restrict__ xaggP, float* __restrict__ full,
    const float* __restrict__ centers, const float* __restrict__ sum_w,
    float* __restrict__ s1) {
  const int k = blockIdx.x, b = blockIdx.y;
  const int tid = threadIdx.x;
  const float sw = sum_w[b * KK + k];
  float4 v = make_float4(0.f, 0.f, 0.f, 0.f);
#pragma unroll
  for (int sp = 0; sp < 8; ++sp) {
    float4 p = *((const float4*)(xaggP + (size_t)((sp * 32 + b) * KK + k) * DD) + tid);
    v.x += p.x; v.y += p.y; v.z += p.z; v.w += p.w;
  }
  float4 c = *((const float4*)(centers + (size_t)k * DD) + tid);
  v.x = fmaf(-sw, c.x, v.x);
  v.y = fmaf(-sw, c.y, v.y);
  v.z = fmaf(-sw, c.z, v.z);
  v.w = fmaf(-sw, c.w, v.w);
  *((float4*)(full + (size_t)(b * KK + k) * DD) + tid) = v;
  float ss = v.x * v.x + v.y * v.y + v.z * v.z + v.w * v.w;
#pragma unroll
  for (int s = 1; s <= 32; s <<= 1) ss += __shfl_xor(ss, s);
  __shared__ float red[2];
  if ((tid & 63) == 0) red[tid >> 6] = ss;
  __syncthreads();
  if (tid == 0) s1[b * KK + k] = red[0] + red[1];
}

// ---------------- K3b: per-(b,k) combined scale ----------------
__global__ __launch_bounds__(64) void nv_k3b(const float* __restrict__ s1,
                                             float* __restrict__ scale) {
  const int b = blockIdx.x, k = threadIdx.x;
  float r = s1[b * KK + k];
  float d1 = fmaxf(r, EPSF);
  float s2 = r / d1;
#pragma unroll
  for (int s = 1; s <= 32; s <<= 1) s2 += __shfl_xor(s2, s);
  scale[b * KK + k] = rsqrtf(d1) * rsqrtf(fmaxf(s2, EPSF));
}

// ---------------- K3c: scale + transpose -> fullT[r][b], coalesced stores ----------------
// block (k, dchunk of 128): stage scaled [32 b][128 d] to LDS, write [128 d][32 b].
__global__ __launch_bounds__(256) void nv_k3c(const float* __restrict__ full,
                                              const float* __restrict__ scale,
                                              float* __restrict__ fullT) {
  const int k = blockIdx.x, d0 = blockIdx.y * 128;
  const int tid = threadIdx.x;
  __shared__ float ls[32 * 132];  // [b][d], pad 132

#pragma unroll
  for (int it = 0; it < 4; ++it) {
    int fi = it * 256 + tid;  // 1024 float4s
    int b = fi >> 5, dg = fi & 31;
    float sc = scale[b * KK + k];
    float4 v = *((const float4*)(full + (size_t)(b * KK + k) * DD + d0) + dg);
    v.x *= sc; v.y *= sc; v.z *= sc; v.w *= sc;
    *(float4*)(ls + b * 132 + dg * 4) = v;
  }
  __syncthreads();
#pragma unroll
  for (int it = 0; it < 4; ++it) {
    int fo = it * 256 + tid;  // 1024 float4s
    int d = fo >> 3, bq = fo & 7;
    float4 v;
    v.x = ls[(bq * 4 + 0) * 132 + d];
    v.y = ls[(bq * 4 + 1) * 132 + d];
    v.z = ls[(bq * 4 + 2) * 132 + d];
    v.w = ls[(bq * 4 + 3) * 132 + d];
    *(float4*)(fullT + (size_t)(k * DD + d0 + d) * 32 + bq * 4) = v;
  }
}

// ---------------- K4: GEMV-bundle, 4-deep load pipeline ----------------
__global__ __launch_bounds__(256) void nv_k4(
    const float* __restrict__ fullT, const float* __restrict__ reduc,
    float* __restrict__ outP) {
  const int strip = blockIdx.x;  // 4
  const int ksp = blockIdx.y;    // 128
  const int tid = threadIdx.x;
  const int wave = tid >> 6, lane = tid & 63;
  const int c0 = strip * 256 + lane * 4;
  const int kblk = ksp * 256;

  __shared__ float fst[256 * 32];  // [k_local][b]; reused as red[32][256]

#pragma unroll
  for (int it = 0; it < 8; ++it) {
    int f4 = it * 256 + tid;
    *(float4*)(fst + f4 * 4) = *(const float4*)(fullT + (size_t)kblk * 32 + f4 * 4);
  }
  __syncthreads();

  float4 acc[32];
#pragma unroll
  for (int b = 0; b < 32; ++b) acc[b] = make_float4(0.f, 0.f, 0.f, 0.f);

  const int kw = wave * 64;
  for (int kk = 0; kk < 64; kk += 4) {
    float4 rv[4];
#pragma unroll
    for (int j = 0; j < 4; ++j)
      rv[j] = *(const float4*)(reduc + (size_t)(kblk + kw + kk + j) * OO + c0);
#pragma unroll
    for (int j = 0; j < 4; ++j) {
      const int kl = kw + kk + j;
#pragma unroll
      for (int b4 = 0; b4 < 8; ++b4) {
        float4 fv = *(const float4*)(fst + kl * 32 + b4 * 4);
        acc[b4 * 4 + 0].x = fmaf(fv.x, rv[j].x, acc[b4 * 4 + 0].x);
        acc[b4 * 4 + 0].y = fmaf(fv.x, rv[j].y, acc[b4 * 4 + 0].y);
        acc[b4 * 4 + 0].z = fmaf(fv.x, rv[j].z, acc[b4 * 4 + 0].z);
        acc[b4 * 4 + 0].w = fmaf(fv.x, rv[j].w, acc[b4 * 4 + 0].w);
        acc[b4 * 4 + 1].x = fmaf(fv.y, rv[j].x, acc[b4 * 4 + 1].x);
        acc[b4 * 4 + 1].y = fmaf(fv.y, rv[j].y, acc[b4 * 4 + 1].y);
        acc[b4 * 4 + 1].z = fmaf(fv.y, rv[j].z, acc[b4 * 4 + 1].z);
        acc[b4 * 4 + 1].w = fmaf(fv.y, rv[j].w, acc[b4 * 4 + 1].w);
        acc[b4 * 4 + 2].x = fmaf(fv.z, rv[j].x, acc[b4 * 4 + 2].x);
        acc[b4 * 4 + 2].y = fmaf(fv.z, rv[j].y, acc[b4 * 4 + 2].y);
        acc[b4 * 4 + 2].z = fmaf(fv.z, rv[j].z, acc[b4 * 4 + 2].z);
        acc[b4 * 4 + 2].w = fmaf(fv.z, rv[j].w, acc[b4 * 4 + 2].w);
        acc[b4 * 4 + 3].x = fmaf(fv.w, rv[j].x, acc[b4 * 4 + 3].x);
        acc[b4 * 4 + 3].y = fmaf(fv.w, rv[j].y, acc[b4 * 4 + 3].y);
        acc[b4 * 4 + 3].z = fmaf(fv.w, rv[j].z, acc[b4 * 4 + 3].z);
        acc[b4 * 4 + 3].w = fmaf(fv.w, rv[j].w, acc[b4 * 4 + 3].w);
      }
    }
  }

  __syncthreads();
  for (int w = 0; w < 4; ++w) {
    if (wave == w) {
      if (w == 0) {
#pragma unroll
        for (int b = 0; b < 32; ++b)
          *(float4*)(fst + b * 256 + lane * 4) = acc[b];
      } else {
#pragma unroll
        for (int b = 0; b < 32; ++b) {
          float4 v = *(float4*)(fst + b * 256 + lane * 4);
          v.x += acc[b].x; v.y += acc[b].y; v.z += acc[b].z; v.w += acc[b].w;
          *(float4*)(fst + b * 256 + lane * 4) = v;
        }
      }
    }
    __syncthreads();
  }

#pragma unroll
  for (int it = 0; it < 8; ++it) {
    int f4 = it * 256 + tid;
    int b = f4 >> 6, cg = f4 & 63;
    *(float4*)(outP + ((size_t)(ksp * 32 + b) * OO) + strip * 256 + cg * 4) =
        *(const float4*)(fst + b * 256 + cg * 4);
  }
}

// ---------------- K5: out = sum over 128 k-splits ----------------
__global__ __launch_bounds__(128) void nv_k5(const float* __restrict__ outP,
                                             float* __restrict__ out) {
  const int idx = blockIdx.x * 128 + threadIdx.x;  // 0..32767
  float s = 0.f;
#pragma unroll 8
  for (int sp = 0; sp < 128; ++sp) s += outP[(size_t)sp * 32768 + idx];
  out[idx] = s;
}

extern "C" void kernel_launch(void* const* d_in, const int* in_sizes, int n_in,
                              void* d_out, int out_size, void* d_ws, size_t ws_size,
                              hipStream_t stream) {
  const float* x = (const float*)d_in[0];
  const float* weight = (const float*)d_in[1];
  const float* bias = (const float*)d_in[2];
  const float* centers = (const float*)d_in[3];
  const float* reduc = (const float*)d_in[4];
  float* out = (float*)d_out;
  float* ws = (float*)d_ws;

  float* xaggP = ws;                          // [0, 8M)
  float* full = ws + 8388608;                 // [8M, 9M)
  float* fullT = ws + 9437184;                // [9M, 10M)
  float* outP = ws + 10485760;                // [10M, 14M)
  ushort* whT = (ushort*)(ws + 14680064);     // 32768 ushorts
  float* sum_w = ws + 14696448;
  float* s1 = sum_w + 2048;
  float* scale = sum_w + 4096;

  nv_k0<<<136, 256, 0, stream>>>(weight, whT, sum_w);
  nv_k12<<<dim3(8, 32), 256, 0, stream>>>(x, whT, bias, xaggP, sum_w);
  nv_k3a<<<dim3(64, 32), 128, 0, stream>>>(xaggP, full, centers, sum_w, s1);
  nv_k3b<<<32, 64, 0, stream>>>(s1, scale);
  nv_k3c<<<dim3(64, 4), 256, 0, stream>>>(full, scale, fullT);
  nv_k4<<<dim3(4, 128), 256, 0, stream>>>(fullT, reduc, outP);
  nv_k5<<<256, 128, 0, stream>>>(outP, out);
}